// Round 8
// baseline (397.824 us; speedup 1.0000x reference)
//
#include <hip/hip_runtime.h>
#include <hip/hip_bf16.h>

#define NN 2048
#define NE 65536
#define NG 32
#define CIN 128
#define CED 32
#define CLAT 64
#define CFA 16
#define CNB 5
#define NL 5

#define OFF_AT (NN * CLAT)
#define OFF_B  (NN * CLAT + NN * CFA)

typedef __attribute__((ext_vector_type(8))) short bf16x8;
typedef __attribute__((ext_vector_type(4))) float f32x4;

__device__ __forceinline__ float silu_f(float v) { return v / (1.0f + __expf(-v)); }
__device__ __forceinline__ short f2bs(float v) {
    __hip_bfloat16 h = __float2bfloat16(v);
    return *reinterpret_cast<short*>(&h);
}
__device__ __forceinline__ unsigned pack2(float a, float b) {
    return ((unsigned)(unsigned short)f2bs(b) << 16) | (unsigned short)f2bs(a);
}

// ---------------- pack weights into MFMA B-fragment order --------------------------------------
// frag layout: [..][nt][lane][8]; k = kt*32 + (lane>>4)*8 + j, n = nt*16 + (lane&15)
// Wproj slot s (0..5): nt0-7 = Wmsg_{s%5} rows0-127 (U); nt8-15 = Wmsg_{s%5} rows128-255 (V);
//                      nt16-17 = Wedge_{s==0?0:s-1} rows0-127 (P); nt18-19 = rows128-255 (Q)
__global__ void k_pack_w(const float* __restrict__ Wmsg, const float* __restrict__ Wedge,
                         const float* __restrict__ Wnode, const float* __restrict__ Wsh,
                         const float* __restrict__ Wal, const float* __restrict__ Wbm,
                         short* __restrict__ Wpn, short* __restrict__ Wpsh,
                         short* __restrict__ Wpal, short* __restrict__ Wpbm,
                         short* __restrict__ Wproj, short* __restrict__ W3m, short* __restrict__ We3)
{
    int idx = blockIdx.x * 256 + threadIdx.x;
    int j = idx & 7, t0 = idx >> 3, lane = t0 & 63, t = t0 >> 6;
    int kq = (lane >> 4) * 8 + j, n16 = lane & 15;
    if (idx < NL * 8 * 8 * 64 * 8) { // Wnode K=256 N=128
        int nt = t & 7, kt = (t >> 3) & 7, l = t >> 6;
        Wpn[idx] = f2bs(Wnode[((size_t)l * 256 + kt * 32 + kq) * CIN + nt * 16 + n16]);
    }
    if (idx < 4 * 8 * 64 * 8) { // Wsh K=128 N=128
        int nt = t & 7, kt = t >> 3;
        Wpsh[idx] = f2bs(Wsh[(size_t)(kt * 32 + kq) * CIN + nt * 16 + n16]);
    }
    if (idx < 4 * 5 * 64 * 8) { // Wal K=128 N=80
        int nt = t % 5, kt = t / 5;
        Wpal[idx] = f2bs(Wal[(size_t)(kt * 32 + kq) * 80 + nt * 16 + n16]);
    }
    if (idx < 8 * 64 * 8) { // Wbm K=32 N=128
        int nt = t & 7;
        Wpbm[idx] = f2bs(Wbm[(size_t)kq * CIN + nt * 16 + n16]);
    }
    if (idx < 6 * 4 * 20 * 64 * 8) { // Wproj: 6 slots, K=128, N=320
        int nt = t % 20; int t2 = t / 20; int kt = t2 & 3; int slot = t2 >> 2;
        int k = kt * 32 + kq;
        float v;
        if (nt < 16) {
            int msgl = slot % 5;
            int srcK = (nt < 8) ? k : 128 + k;
            int col = (nt & 7) * 16 + n16;
            v = Wmsg[((size_t)msgl * 288 + srcK) * CIN + col];
        } else {
            int edgel = (slot == 0) ? 0 : slot - 1;
            int srcK = (nt < 18) ? k : 128 + k;
            int col = (nt & 1) * 16 + n16;
            v = Wedge[((size_t)edgel * 288 + srcK) * CED + col];
        }
        Wproj[idx] = f2bs(v);
    }
    if (idx < NL * 8 * 64 * 8) { // W3m: Wmsg rows 256..287, K=32 N=128
        int nt = t & 7, l = t >> 3;
        W3m[idx] = f2bs(Wmsg[((size_t)l * 288 + 256 + kq) * CIN + nt * 16 + n16]);
    }
    if (idx < NL * 2 * 64 * 8) { // We3: Wedge rows 256..287, K=32 N=32
        int nt = t & 1, l = t >> 1;
        We3[idx] = f2bs(Wedge[((size_t)l * 288 + 256 + kq) * CED + nt * 16 + n16]);
    }
}

// ---------------- init s: 16 nodes/block, register-blocked GEMV --------------------------------
__global__ __launch_bounds__(128) void k_init_s(
    const float* __restrict__ x, const float* __restrict__ t,
    const float* __restrict__ z, const int* __restrict__ batch,
    const float* __restrict__ Wt_a, const float* __restrict__ bt_a,
    const float* __restrict__ W_atom, const float* __restrict__ b_atom,
    const float* __restrict__ W_lat, const float* __restrict__ b_lat,
    const float* __restrict__ W_at, const float* __restrict__ b_at,
    float* __restrict__ s, short* __restrict__ s_bf)
{
    const int NB = 16;
    int nb0 = blockIdx.x * NB, c = threadIdx.x;
    __shared__ float xs[NB * CFA];
    __shared__ float zs[NB * CLAT];
    __shared__ float tmp[NB * CIN];
    __shared__ float tv[NB];
    if (c < NB * CFA / 4) ((float4*)xs)[c] = ((const float4*)x)[nb0 * (CFA / 4) + c];
    for (int q = c; q < NB * CLAT / 4; q += 128) ((float4*)zs)[q] = ((const float4*)z)[nb0 * (CLAT / 4) + q];
    if (c < NB) tv[c] = t[batch[nb0 + c]];
    __syncthreads();
    float wta = Wt_a[c], base0 = b_atom[c] + bt_a[c];
    float acc[NB];
#pragma unroll
    for (int nd = 0; nd < NB; nd++) acc[nd] = base0 + tv[nd] * wta;
    for (int k = 0; k < CFA; k++) {
        float w = W_atom[k * CIN + c];
#pragma unroll
        for (int nd = 0; nd < NB; nd++) acc[nd] += xs[nd * CFA + k] * w;
    }
#pragma unroll
    for (int nd = 0; nd < NB; nd++) tmp[nd * CIN + c] = acc[nd];
    __syncthreads();
    float base1 = b_at[c] + b_lat[c];
    float acc2[NB];
#pragma unroll
    for (int nd = 0; nd < NB; nd++) acc2[nd] = base1;
    for (int k4 = 0; k4 < CIN / 4; k4++) {
        float w0 = W_at[(4 * k4 + 0) * CIN + c], w1 = W_at[(4 * k4 + 1) * CIN + c];
        float w2 = W_at[(4 * k4 + 2) * CIN + c], w3 = W_at[(4 * k4 + 3) * CIN + c];
#pragma unroll
        for (int nd = 0; nd < NB; nd++) {
            float4 f = *(const float4*)&tmp[nd * CIN + 4 * k4];
            acc2[nd] += f.x * w0 + f.y * w1 + f.z * w2 + f.w * w3;
        }
    }
    for (int k4 = 0; k4 < CLAT / 4; k4++) {
        float w0 = W_lat[(4 * k4 + 0) * CIN + c], w1 = W_lat[(4 * k4 + 1) * CIN + c];
        float w2 = W_lat[(4 * k4 + 2) * CIN + c], w3 = W_lat[(4 * k4 + 3) * CIN + c];
#pragma unroll
        for (int nd = 0; nd < NB; nd++) {
            float4 f = *(const float4*)&zs[nd * CLAT + 4 * k4];
            acc2[nd] += f.x * w0 + f.y * w1 + f.z * w2 + f.w * w3;
        }
    }
#pragma unroll
    for (int nd = 0; nd < NB; nd++) {
        s[(nb0 + nd) * CIN + c] = acc2[nd];
        s_bf[(nb0 + nd) * CIN + c] = f2bs(acc2[nd]);
    }
}

// ---------------- init e (+bf16 shadow) + map scatter + degree count ---------------------------
__global__ void k_init_e(const float* __restrict__ ea, const float* __restrict__ t,
                         const int* __restrict__ beg, const int* __restrict__ jj, const int* __restrict__ ii,
                         const float* __restrict__ Wt_b, const float* __restrict__ bt_b,
                         const float* __restrict__ W_bond, const float* __restrict__ b_bond,
                         const float* __restrict__ W_bt, const float* __restrict__ b_bt,
                         float* __restrict__ e, short* __restrict__ e_bf, int* __restrict__ map,
                         int* __restrict__ cnt)
{
    int le = threadIdx.x >> 5, c = threadIdx.x & 31;
    int k = blockIdx.x * 8 + le;
    __shared__ float tmp[8][CED];
    float tg = t[beg[k]];
    float acc = b_bond[c] + tg * Wt_b[c] + bt_b[c];
#pragma unroll
    for (int b = 0; b < CNB; b++) acc += ea[k * CNB + b] * W_bond[b * CED + c];
    tmp[le][c] = acc;
    __syncthreads();
    float acc2 = b_bt[c];
#pragma unroll
    for (int d = 0; d < CED; d++) acc2 += tmp[le][d] * W_bt[d * CED + c];
    e[k * CED + c] = acc2;
    e_bf[k * CED + c] = f2bs(acc2);
    if (c == 0) {
        atomicMax(&map[jj[k] * NN + ii[k]], k);
        atomicAdd(&cnt[ii[k]], 1);
    }
}

// ---------------- prefix sum over cnt[2048] -> rowpos (exclusive) ------------------------------
__global__ __launch_bounds__(256) void k_prefix(const int* __restrict__ cnt, int* __restrict__ rowpos)
{
    __shared__ int part[256];
    int tid = threadIdx.x;
    int loc[8], sum = 0;
#pragma unroll
    for (int q = 0; q < 8; q++) { loc[q] = cnt[tid * 8 + q]; sum += loc[q]; }
    part[tid] = sum;
    __syncthreads();
    if (tid == 0) {
        int r = 0;
        for (int i = 0; i < 256; i++) { int v = part[i]; part[i] = r; r += v; }
    }
    __syncthreads();
    int r = part[tid];
#pragma unroll
    for (int q = 0; q < 8; q++) { rowpos[tid * 8 + q] = r; r += loc[q]; }
}

// ---------------- build perm: edges sorted by target i -----------------------------------------
__global__ void k_perm(const int* __restrict__ ii, int* __restrict__ rowpos, int* __restrict__ perm)
{
    int k = blockIdx.x * 256 + threadIdx.x;
    if (k < NE) {
        int p = atomicAdd(&rowpos[ii[k]], 1);
        perm[p] = k;
    }
}

// ---------------- node update + projections: 16 rows/block, waves split N ----------------------
template<bool DO_NODE>
__global__ __launch_bounds__(256) void k_node_proj(
    float* __restrict__ s, short* __restrict__ s_bf, float* __restrict__ agg,
    const short* __restrict__ Wpn_l, const float* __restrict__ bnode_l,
    const short* __restrict__ Wproj, float* __restrict__ U, float* __restrict__ V,
    float* __restrict__ P, float* __restrict__ Q)
{
    __shared__ short feat[16 * 264];
    __shared__ short feat2[16 * 136];
    int tid = threadIdx.x;
    int nb0 = blockIdx.x * 16;
    int lane = tid & 63, w = tid >> 6;
    int quad = lane >> 4, n16 = lane & 15;

    if (DO_NODE) {
        { // s_bf tile: 16 rows x 16 uint4
            int kl = tid >> 4, c = tid & 15;
            *(uint4*)&feat[kl * 264 + c * 8] = ((const uint4*)s_bf)[(size_t)(nb0 + kl) * 16 + c];
        }
        for (int idx = tid; idx < 16 * 32; idx += 256) { // agg -> bf16, zero agg
            int kl = idx >> 5, c = idx & 31;
            size_t gix = (size_t)(nb0 + kl) * 32 + c;
            float4 v = ((const float4*)agg)[gix];
            ((float4*)agg)[gix] = (float4){0.f, 0.f, 0.f, 0.f};
            uint2 p; p.x = pack2(v.x, v.y); p.y = pack2(v.z, v.w);
            *(uint2*)&feat[kl * 264 + 128 + 4 * c] = p;
        }
        __syncthreads();
        f32x4 acc[2];
        acc[0] = (f32x4){0.f, 0.f, 0.f, 0.f};
        acc[1] = (f32x4){0.f, 0.f, 0.f, 0.f};
        const short* fbase = feat + n16 * 264 + quad * 8;
#pragma unroll
        for (int kt = 0; kt < 8; kt++) {
            bf16x8 a = *(const bf16x8*)(fbase + kt * 32);
#pragma unroll
            for (int n2 = 0; n2 < 2; n2++) {
                int nt = w * 2 + n2;
                bf16x8 b = *(const bf16x8*)(Wpn_l + ((size_t)(kt * 8 + nt) * 64 + lane) * 8);
                acc[n2] = __builtin_amdgcn_mfma_f32_16x16x32_bf16(a, b, acc[n2], 0, 0, 0);
            }
        }
#pragma unroll
        for (int n2 = 0; n2 < 2; n2++) {
            int col = (w * 2 + n2) * 16 + n16;
            float bb = bnode_l[col];
#pragma unroll
            for (int r = 0; r < 4; r++) {
                int row = quad * 4 + r;
                size_t ix = (size_t)(nb0 + row) * CIN + col;
                float v = s[ix] + silu_f(acc[n2][r] + bb);
                s[ix] = v;
                short bv = f2bs(v);
                s_bf[ix] = bv;
                feat2[row * 136 + col] = bv;
            }
        }
        __syncthreads();
    } else {
        int kl = tid >> 4, c = tid & 15;
        *(uint4*)&feat2[kl * 136 + c * 8] = ((const uint4*)s_bf)[(size_t)(nb0 + kl) * 16 + c];
        __syncthreads();
    }

    // projections: [U|V|P|Q] = s_new @ Wproj (K=128, N=320); wave w -> nt 5w..5w+4
    f32x4 accp[5];
#pragma unroll
    for (int t2 = 0; t2 < 5; t2++) accp[t2] = (f32x4){0.f, 0.f, 0.f, 0.f};
    const short* abase = feat2 + n16 * 136 + quad * 8;
#pragma unroll
    for (int kt = 0; kt < 4; kt++) {
        bf16x8 a = *(const bf16x8*)(abase + kt * 32);
#pragma unroll
        for (int n5 = 0; n5 < 5; n5++) {
            int nt = w * 5 + n5;
            bf16x8 b = *(const bf16x8*)(Wproj + ((size_t)(kt * 20 + nt) * 64 + lane) * 8);
            accp[n5] = __builtin_amdgcn_mfma_f32_16x16x32_bf16(a, b, accp[n5], 0, 0, 0);
        }
    }
#pragma unroll
    for (int n5 = 0; n5 < 5; n5++) {
        int nt = w * 5 + n5;
#pragma unroll
        for (int r = 0; r < 4; r++) {
            int node = nb0 + quad * 4 + r;
            float v = accp[n5][r];
            if (nt < 8)       U[(size_t)node * CIN + nt * 16 + n16] = v;
            else if (nt < 16) V[(size_t)node * CIN + (nt - 8) * 16 + n16] = v;
            else if (nt < 18) P[(size_t)node * CED + (nt - 16) * 16 + n16] = v;
            else              Q[(size_t)node * CED + (nt - 18) * 16 + n16] = v;
        }
    }
}

// ---------------- per-edge: [edge update] + [msg + segment sum], K=32 GEMMs --------------------
// Bias rows staged cooperatively: uv = U[i]+V[j] (also reused as msg-value buffer), pq = P[i]+Q[j].
template<bool DO_EDGE, bool DO_MSG>
__global__ __launch_bounds__(256) void k_em(
    const short* __restrict__ e_bf_in,
    const int* __restrict__ ii, const int* __restrict__ jj, const int* __restrict__ perm,
    const short* __restrict__ We3p, const float* __restrict__ bedge,
    const float* __restrict__ P, const float* __restrict__ Q,
    float* __restrict__ e, short* __restrict__ e_bf,
    const short* __restrict__ W3mp, const float* __restrict__ bmsg,
    const float* __restrict__ U, const float* __restrict__ V,
    float* __restrict__ agg)
{
    __shared__ short feat_e[64 * 40]; // e rows bf16 (32 used, pad 40)
    __shared__ float uv[64 * 132];    // U[i]+V[j]; after msg epilogue holds m values
    __shared__ float pq[64 * 36];     // P[i]+Q[j]
    __shared__ int sii[64], sjj[64], sek[64];
    int tid = threadIdx.x;
    int e0 = blockIdx.x * 64;
    if (tid < 64) {
        int k = perm[e0 + tid];
        sek[tid] = k;
        sii[tid] = ii[k]; // sorted non-decreasing
        sjj[tid] = jj[k];
    }
    __syncthreads();
    { // stage e rows: 4 uint4 per row
        int kl = tid >> 2, c = tid & 3;
        uint4 v = ((const uint4*)e_bf_in)[(size_t)sek[kl] * 4 + c];
        *(uint4*)&feat_e[kl * 40 + c * 8] = v;
    }
    if (DO_EDGE) {
        for (int idx = tid; idx < 64 * 8; idx += 256) { // pq rows: 8 float4 each
            int kl = idx >> 3, c = idx & 7;
            float4 a = ((const float4*)P)[(size_t)sii[kl] * 8 + c];
            float4 b = ((const float4*)Q)[(size_t)sjj[kl] * 8 + c];
            *(float4*)&pq[kl * 36 + 4 * c] = (float4){a.x + b.x, a.y + b.y, a.z + b.z, a.w + b.w};
        }
    }
    if (DO_MSG) {
        for (int idx = tid; idx < 64 * 32; idx += 256) { // uv rows: 32 float4 each
            int kl = idx >> 5, c = idx & 31;
            float4 a = ((const float4*)U)[(size_t)sii[kl] * 32 + c];
            float4 b = ((const float4*)V)[(size_t)sjj[kl] * 32 + c];
            *(float4*)&uv[kl * 132 + 4 * c] = (float4){a.x + b.x, a.y + b.y, a.z + b.z, a.w + b.w};
        }
    }
    __syncthreads();
    int lane = tid & 63, w = tid >> 6;
    int quad = lane >> 4, n16 = lane & 15;
    const short* abase = feat_e + (w * 16 + n16) * 40 + quad * 8;
    bf16x8 a = *(const bf16x8*)abase;

    if (DO_EDGE) {
        f32x4 acc_e[2];
        acc_e[0] = (f32x4){0.f, 0.f, 0.f, 0.f};
        acc_e[1] = (f32x4){0.f, 0.f, 0.f, 0.f};
#pragma unroll
        for (int nt = 0; nt < 2; nt++) {
            bf16x8 b = *(const bf16x8*)(We3p + ((size_t)(nt * 64 + lane)) * 8);
            acc_e[nt] = __builtin_amdgcn_mfma_f32_16x16x32_bf16(a, b, acc_e[nt], 0, 0, 0);
        }
#pragma unroll
        for (int nt = 0; nt < 2; nt++) {
            int ch = nt * 16 + n16;
            float bb = bedge[ch];
#pragma unroll
            for (int r = 0; r < 4; r++) {
                int el = w * 16 + quad * 4 + r; // own-wave row
                size_t ix = (size_t)sek[el] * CED + ch;
                float v = e[ix] + silu_f(acc_e[nt][r] + bb + pq[el * 36 + ch]);
                e[ix] = v;
                short bv = f2bs(v);
                e_bf[ix] = bv;
                feat_e[el * 40 + ch] = bv; // patch for msg A
            }
        }
        a = *(const bf16x8*)abase; // re-read patched row (own-wave rows; lgkmcnt ordered)
    }

    if (DO_MSG) {
        f32x4 acc_m[8];
#pragma unroll
        for (int t2 = 0; t2 < 8; t2++) acc_m[t2] = (f32x4){0.f, 0.f, 0.f, 0.f};
#pragma unroll
        for (int nt = 0; nt < 8; nt++) {
            bf16x8 b = *(const bf16x8*)(W3mp + ((size_t)(nt * 64 + lane)) * 8);
            acc_m[nt] = __builtin_amdgcn_mfma_f32_16x16x32_bf16(a, b, acc_m[nt], 0, 0, 0);
        }
#pragma unroll
        for (int nt = 0; nt < 8; nt++) {
            int ch = nt * 16 + n16;
            float bb = bmsg[ch];
#pragma unroll
            for (int r = 0; r < 4; r++) {
                int el = w * 16 + quad * 4 + r;
                int lix = el * 132 + ch;
                float m = silu_f(acc_m[nt][r] + bb + uv[lix]); // each (el,ch) owned by one thread
                uv[lix] = m;
            }
        }
        __syncthreads();
        if (tid < 128) { // group-reduce by sorted target
            int c = tid;
            float run = 0.f;
            int cur = sii[0];
            for (int r = 0; r < 64; r++) {
                int tg = sii[r];
                if (tg != cur) { atomicAdd(&agg[(size_t)cur * CIN + c], run); run = 0.f; cur = tg; }
                run += uv[r * 132 + c];
            }
            atomicAdd(&agg[(size_t)cur * CIN + c], run);
        }
    }
}

// ---------------- post node: 16 rows/block, waves split N --------------------------------------
__global__ __launch_bounds__(256) void k_post_node_mfma(
    const short* __restrict__ s_bf,
    const short* __restrict__ Wpsh, const float* __restrict__ bsh,
    const short* __restrict__ Wpal, const float* __restrict__ bal,
    float* __restrict__ s2, float* __restrict__ out)
{
    __shared__ short feat[16 * 136];
    __shared__ short feat_s2[16 * 136];
    int tid = threadIdx.x;
    int nb0 = blockIdx.x * 16;
    int lane = tid & 63, w = tid >> 6;
    int quad = lane >> 4, n16 = lane & 15;
    {
        int kl = tid >> 4, c = tid & 15;
        *(uint4*)&feat[kl * 136 + c * 8] = ((const uint4*)s_bf)[(size_t)(nb0 + kl) * 16 + c];
    }
    __syncthreads();
    const short* fbase = feat + n16 * 136 + quad * 8;
    f32x4 acc[2];
    acc[0] = (f32x4){0.f, 0.f, 0.f, 0.f};
    acc[1] = (f32x4){0.f, 0.f, 0.f, 0.f};
#pragma unroll
    for (int kt = 0; kt < 4; kt++) {
        bf16x8 a = *(const bf16x8*)(fbase + kt * 32);
#pragma unroll
        for (int n2 = 0; n2 < 2; n2++) {
            int nt = w * 2 + n2;
            bf16x8 b = *(const bf16x8*)(Wpsh + ((size_t)(kt * 8 + nt) * 64 + lane) * 8);
            acc[n2] = __builtin_amdgcn_mfma_f32_16x16x32_bf16(a, b, acc[n2], 0, 0, 0);
        }
    }
#pragma unroll
    for (int n2 = 0; n2 < 2; n2++) {
        int col = (w * 2 + n2) * 16 + n16;
        float bb = bsh[col];
#pragma unroll
        for (int r = 0; r < 4; r++) {
            int row = quad * 4 + r;
            float v = silu_f(acc[n2][r] + bb);
            s2[(size_t)(nb0 + row) * CIN + col] = v;
            feat_s2[row * 136 + col] = f2bs(v);
        }
    }
    __syncthreads();
    const short* abase = feat_s2 + n16 * 136 + quad * 8;
    f32x4 acca[2];
    acca[0] = (f32x4){0.f, 0.f, 0.f, 0.f};
    acca[1] = (f32x4){0.f, 0.f, 0.f, 0.f};
    int nAl = (w == 0) ? 2 : 1;
    int ntl[2] = {w, 4};
#pragma unroll
    for (int kt = 0; kt < 4; kt++) {
        bf16x8 a = *(const bf16x8*)(abase + kt * 32);
#pragma unroll
        for (int q = 0; q < 2; q++) {
            if (q < nAl) {
                bf16x8 b = *(const bf16x8*)(Wpal + ((size_t)(kt * 5 + ntl[q]) * 64 + lane) * 8);
                acca[q] = __builtin_amdgcn_mfma_f32_16x16x32_bf16(a, b, acca[q], 0, 0, 0);
            }
        }
    }
#pragma unroll
    for (int q = 0; q < 2; q++) {
        if (q < nAl) {
            int col = ntl[q] * 16 + n16;
            float bb = bal[col];
#pragma unroll
            for (int r = 0; r < 4; r++) {
                int node = nb0 + quad * 4 + r;
                float v = acca[q][r] + bb;
                if (col < CFA) out[OFF_AT + node * CFA + col] = v;
                else           out[(size_t)node * CLAT + (col - CFA)] = v;
            }
        }
    }
}

// ---------------- post edge (MFMA): esym@Wbm + silu + Wbl tail ---------------------------------
__global__ __launch_bounds__(256) void k_post_edge_mfma(
    const float* __restrict__ s2, const float* __restrict__ e,
    const int* __restrict__ ii, const int* __restrict__ jj, const int* __restrict__ map,
    const short* __restrict__ Wpbm, const float* __restrict__ bbm,
    const float* __restrict__ Wbl, const float* __restrict__ bbl,
    float* __restrict__ out)
{
    __shared__ int sii[64], sjj[64], skf[64], skb[64];
    __shared__ short esym[64 * 40];
    __shared__ float sbias[64 * 132]; // later aliased as fshT[128][66]
    int tid = threadIdx.x;
    int e0 = blockIdx.x * 64;
    if (tid < 64) sii[tid] = ii[e0 + tid];
    else if (tid < 128) sjj[tid - 64] = jj[e0 + tid - 64];
    __syncthreads();
    if (tid < 64) skf[tid] = map[(size_t)sjj[tid] * NN + sii[tid]];
    else if (tid < 128) skb[tid - 64] = map[(size_t)sii[tid - 64] * NN + sjj[tid - 64]];
    __syncthreads();
    for (int idx = tid; idx < 64 * 8; idx += 256) {
        int kl = idx >> 3, c = idx & 7;
        float4 a = ((const float4*)e)[(size_t)skf[kl] * 8 + c];
        int kb = skb[kl];
        float4 b = {0.f, 0.f, 0.f, 0.f};
        if (kb >= 0) b = ((const float4*)e)[(size_t)kb * 8 + c];
        uint2 p; p.x = pack2(0.5f * (a.x + b.x), 0.5f * (a.y + b.y));
        p.y = pack2(0.5f * (a.z + b.z), 0.5f * (a.w + b.w));
        *(uint2*)&esym[kl * 40 + 4 * c] = p;
    }
    for (int idx = tid; idx < 64 * 32; idx += 256) {
        int kl = idx >> 5, c = idx & 31;
        float4 a = ((const float4*)s2)[(size_t)sii[kl] * 32 + c];
        float4 b = ((const float4*)s2)[(size_t)sjj[kl] * 32 + c];
        float4 v = {a.x + b.x, a.y + b.y, a.z + b.z, a.w + b.w};
        *(float4*)&sbias[kl * 132 + 4 * c] = v;
    }
    __syncthreads();
    int lane = tid & 63, w = tid >> 6;
    int quad = lane >> 4, n16 = lane & 15;
    bf16x8 a = *(const bf16x8*)(esym + (w * 16 + n16) * 40 + quad * 8);
    f32x4 acc[8];
#pragma unroll
    for (int nt = 0; nt < 8; nt++) {
        bf16x8 b = *(const bf16x8*)(Wpbm + ((size_t)nt * 64 + lane) * 8);
        f32x4 zero = {0.f, 0.f, 0.f, 0.f};
        acc[nt] = __builtin_amdgcn_mfma_f32_16x16x32_bf16(a, b, zero, 0, 0, 0);
    }
    float f[8][4];
#pragma unroll
    for (int nt = 0; nt < 8; nt++) {
        int col = nt * 16 + n16;
        float bb = bbm[col];
#pragma unroll
        for (int r = 0; r < 4; r++) {
            int row = w * 16 + quad * 4 + r;
            f[nt][r] = silu_f(acc[nt][r] + bb + sbias[row * 132 + col]);
        }
    }
    __syncthreads();
    float* fshT = sbias;
#pragma unroll
    for (int nt = 0; nt < 8; nt++) {
        int col = nt * 16 + n16;
#pragma unroll
        for (int r = 0; r < 4; r++) {
            int row = w * 16 + quad * 4 + r;
            fshT[col * 66 + row] = f[nt][r];
        }
    }
    __syncthreads();
    for (int idx = tid; idx < 64 * CNB; idx += 256) {
        int kl = idx / CNB, b = idx - kl * CNB;
        float acc3 = bbl[b];
        for (int d = 0; d < CIN; d++) acc3 += fshT[d * 66 + kl] * Wbl[d * CNB + b];
        out[OFF_B + (size_t)(e0 + kl) * CNB + b] = acc3;
    }
}

extern "C" void kernel_launch(void* const* d_in, const int* in_sizes, int n_in,
                              void* d_out, int out_size, void* d_ws, size_t ws_size,
                              hipStream_t stream) {
    const float* x      = (const float*)d_in[0];
    const float* t      = (const float*)d_in[1];
    const float* z      = (const float*)d_in[2];
    const int*   eidx   = (const int*)d_in[3];
    const int*   jj     = eidx;        // edge_index[0] = j
    const int*   ii     = eidx + NE;   // edge_index[1] = i
    const float* ea     = (const float*)d_in[4];
    const int*   batch  = (const int*)d_in[5];
    const int*   beg    = (const int*)d_in[6];
    const float* Wt_a   = (const float*)d_in[7];
    const float* bt_a   = (const float*)d_in[8];
    const float* Wt_b   = (const float*)d_in[9];
    const float* bt_b   = (const float*)d_in[10];
    const float* W_atom = (const float*)d_in[11];
    const float* b_atom = (const float*)d_in[12];
    const float* W_bond = (const float*)d_in[13];
    const float* b_bond = (const float*)d_in[14];
    const float* W_lat  = (const float*)d_in[15];
    const float* b_lat  = (const float*)d_in[16];
    const float* W_at   = (const float*)d_in[17];
    const float* b_at   = (const float*)d_in[18];
    const float* W_bt   = (const float*)d_in[19];
    const float* b_bt   = (const float*)d_in[20];
    const float* Wmsg   = (const float*)d_in[21];
    const float* bmsg   = (const float*)d_in[22];
    const float* Wnode  = (const float*)d_in[23];
    const float* bnode  = (const float*)d_in[24];
    const float* Wedge  = (const float*)d_in[25];
    const float* bedge  = (const float*)d_in[26];
    const float* Wsh    = (const float*)d_in[27];
    const float* bsh    = (const float*)d_in[28];
    const float* Wbm    = (const float*)d_in[29];
    const float* bbm    = (const float*)d_in[30];
    const float* Wbl    = (const float*)d_in[31];
    const float* bbl    = (const float*)d_in[32];
    const float* Wal    = (const float*)d_in[33];
    const float* bal    = (const float*)d_in[34];

    float* s      = (float*)d_ws;                       // N*128 f32
    float* e      = s + (size_t)NN * CIN;               // E*32 f32
    float* agg    = e + (size_t)NE * CED;               // N*128 f32
    int*   cnt    = (int*)(agg + (size_t)NN * CIN);     // N (zeroed with agg)
    int*   rowpos = cnt + NN;                           // N
    int*   perm   = rowpos + NN;                        // E
    float* s2     = (float*)(perm + NE);                // N*128
    float* U      = s2 + (size_t)NN * CIN;              // N*128
    float* V      = U + (size_t)NN * CIN;               // N*128
    float* P      = V + (size_t)NN * CIN;               // N*32
    float* Q      = P + (size_t)NN * CED;               // N*32
    int*   map    = (int*)(Q + (size_t)NN * CED);       // N*N
    short* s_bf   = (short*)(map + (size_t)NN * NN);    // N*128 bf16
    short* e_bf   = s_bf + (size_t)NN * CIN;            // E*32 bf16
    short* Wpn    = e_bf + (size_t)NE * CED;            // 163840
    short* Wpsh   = Wpn + (size_t)NL * 8 * 8 * 64 * 8;  // 16384
    short* Wpal   = Wpsh + (size_t)4 * 8 * 64 * 8;      // 10240
    short* Wpbm   = Wpal + (size_t)4 * 5 * 64 * 8;      // 4096
    short* Wproj  = Wpbm + (size_t)8 * 64 * 8;          // 245760 (6 slots x 40960)
    short* W3m    = Wproj + (size_t)6 * 4 * 20 * 64 * 8;// 20480
    short* We3    = W3m + (size_t)NL * 8 * 64 * 8;      // 5120
    float* out    = (float*)d_out;

    hipMemsetAsync(map, 0xFF, (size_t)NN * NN * sizeof(int), stream);
    hipMemsetAsync(agg, 0, ((size_t)NN * CIN + NN) * sizeof(float), stream);
    k_pack_w<<<960, 256, 0, stream>>>(Wmsg, Wedge, Wnode, Wsh, Wal, Wbm,
                                      Wpn, Wpsh, Wpal, Wpbm, Wproj, W3m, We3);
    k_init_s<<<NN / 16, 128, 0, stream>>>(x, t, z, batch, Wt_a, bt_a, W_atom, b_atom,
                                          W_lat, b_lat, W_at, b_at, s, s_bf);
    k_init_e<<<NE / 8, 256, 0, stream>>>(ea, t, beg, jj, ii, Wt_b, bt_b, W_bond, b_bond,
                                         W_bt, b_bt, e, e_bf, map, cnt);
    k_prefix<<<1, 256, 0, stream>>>(cnt, rowpos);
    k_perm<<<NE / 256, 256, 0, stream>>>(ii, rowpos, perm);

    // proj0: U,V from s_0 with Wmsg_0 (slot 0)
    k_node_proj<false><<<NN / 16, 256, 0, stream>>>(s, s_bf, agg, nullptr, nullptr,
                                                    Wproj, U, V, P, Q);
    // msg0
    k_em<false, true><<<NE / 64, 256, 0, stream>>>(e_bf, ii, jj, perm,
                                                   nullptr, nullptr, P, Q, e, e_bf,
                                                   W3m, bmsg, U, V, agg);
    for (int l = 0; l < NL; l++) {
        // node_l + projections (slot l+1: msg_{l+1}, edge_l)
        k_node_proj<true><<<NN / 16, 256, 0, stream>>>(s, s_bf, agg,
                                                       Wpn + (size_t)l * 8 * 8 * 64 * 8,
                                                       bnode + l * CIN,
                                                       Wproj + (size_t)(l + 1) * 4 * 20 * 64 * 8,
                                                       U, V, P, Q);
        if (l < NL - 1) {
            k_em<true, true><<<NE / 64, 256, 0, stream>>>(e_bf, ii, jj, perm,
                                                          We3 + (size_t)l * 2 * 64 * 8,
                                                          bedge + l * CED, P, Q, e, e_bf,
                                                          W3m + (size_t)(l + 1) * 8 * 64 * 8,
                                                          bmsg + (l + 1) * CIN, U, V, agg);
        } else {
            k_em<true, false><<<NE / 64, 256, 0, stream>>>(e_bf, ii, jj, perm,
                                                           We3 + (size_t)l * 2 * 64 * 8,
                                                           bedge + l * CED, P, Q, e, e_bf,
                                                           nullptr, nullptr, nullptr, nullptr, agg);
        }
    }
    k_post_node_mfma<<<NN / 16, 256, 0, stream>>>(s_bf, Wpsh, bsh, Wpal, bal, s2, out);
    k_post_edge_mfma<<<NE / 64, 256, 0, stream>>>(s2, e, ii, jj, map, Wpbm, bbm, Wbl, bbl, out);
}

// Round 9
// 383.826 us; speedup vs baseline: 1.0365x; 1.0365x over previous
//
#include <hip/hip_runtime.h>
#include <hip/hip_bf16.h>

#define NN 2048
#define NE 65536
#define NG 32
#define CIN 128
#define CED 32
#define CLAT 64
#define CFA 16
#define CNB 5
#define NL 5

#define OFF_AT (NN * CLAT)
#define OFF_B  (NN * CLAT + NN * CFA)

typedef __attribute__((ext_vector_type(8))) short bf16x8;
typedef __attribute__((ext_vector_type(4))) float f32x4;

__device__ __forceinline__ float silu_f(float v) { return v / (1.0f + __expf(-v)); }
__device__ __forceinline__ short f2bs(float v) {
    __hip_bfloat16 h = __float2bfloat16(v);
    return *reinterpret_cast<short*>(&h);
}
__device__ __forceinline__ unsigned pack2(float a, float b) {
    return ((unsigned)(unsigned short)f2bs(b) << 16) | (unsigned short)f2bs(a);
}

// ---------------- fused prologue: [0,960) pack weights | [960,1088) init_s | [1088,1152) cnt ---
// pack frag layout: [..][nt][lane][8]; k = kt*32 + (lane>>4)*8 + j, n = nt*16 + (lane&15)
__global__ __launch_bounds__(256) void k_prologue(
    const float* __restrict__ Wmsg, const float* __restrict__ Wedge,
    const float* __restrict__ Wnode, const float* __restrict__ Wsh,
    const float* __restrict__ Wal, const float* __restrict__ Wbm,
    short* __restrict__ Wpn, short* __restrict__ Wpsh,
    short* __restrict__ Wpal, short* __restrict__ Wpbm,
    short* __restrict__ Wproj, short* __restrict__ W3m, short* __restrict__ We3,
    const float* __restrict__ x, const float* __restrict__ t,
    const float* __restrict__ z, const int* __restrict__ batch,
    const float* __restrict__ Wt_a, const float* __restrict__ bt_a,
    const float* __restrict__ W_atom, const float* __restrict__ b_atom,
    const float* __restrict__ W_lat, const float* __restrict__ b_lat,
    const float* __restrict__ W_at, const float* __restrict__ b_at,
    float* __restrict__ s, short* __restrict__ s_bf,
    const int* __restrict__ ii, int* __restrict__ cnt)
{
    int b = blockIdx.x, tid = threadIdx.x;
    if (b < 960) { // ---- pack ----
        int idx = b * 256 + tid;
        int j = idx & 7, t0 = idx >> 3, lane = t0 & 63, tt = t0 >> 6;
        int kq = (lane >> 4) * 8 + j, n16 = lane & 15;
        if (idx < NL * 8 * 8 * 64 * 8) { // Wnode K=256 N=128
            int nt = tt & 7, kt = (tt >> 3) & 7, l = tt >> 6;
            Wpn[idx] = f2bs(Wnode[((size_t)l * 256 + kt * 32 + kq) * CIN + nt * 16 + n16]);
        }
        if (idx < 4 * 8 * 64 * 8) { // Wsh K=128 N=128
            int nt = tt & 7, kt = tt >> 3;
            Wpsh[idx] = f2bs(Wsh[(size_t)(kt * 32 + kq) * CIN + nt * 16 + n16]);
        }
        if (idx < 4 * 5 * 64 * 8) { // Wal K=128 N=80
            int nt = tt % 5, kt = tt / 5;
            Wpal[idx] = f2bs(Wal[(size_t)(kt * 32 + kq) * 80 + nt * 16 + n16]);
        }
        if (idx < 8 * 64 * 8) { // Wbm K=32 N=128
            int nt = tt & 7;
            Wpbm[idx] = f2bs(Wbm[(size_t)kq * CIN + nt * 16 + n16]);
        }
        if (idx < 6 * 4 * 20 * 64 * 8) { // Wproj: 6 slots, K=128, N=320
            int nt = tt % 20; int t2 = tt / 20; int kt = t2 & 3; int slot = t2 >> 2;
            int k = kt * 32 + kq;
            float v;
            if (nt < 16) {
                int msgl = slot % 5;
                int srcK = (nt < 8) ? k : 128 + k;
                int col = (nt & 7) * 16 + n16;
                v = Wmsg[((size_t)msgl * 288 + srcK) * CIN + col];
            } else {
                int edgel = (slot == 0) ? 0 : slot - 1;
                int srcK = (nt < 18) ? k : 128 + k;
                int col = (nt & 1) * 16 + n16;
                v = Wedge[((size_t)edgel * 288 + srcK) * CED + col];
            }
            Wproj[idx] = f2bs(v);
        }
        if (idx < NL * 8 * 64 * 8) { // W3m: Wmsg rows 256..287, K=32 N=128
            int nt = tt & 7, l = tt >> 3;
            W3m[idx] = f2bs(Wmsg[((size_t)l * 288 + 256 + kq) * CIN + nt * 16 + n16]);
        }
        if (idx < NL * 2 * 64 * 8) { // We3: Wedge rows 256..287, K=32 N=32
            int nt = tt & 1, l = tt >> 1;
            We3[idx] = f2bs(Wedge[((size_t)l * 288 + 256 + kq) * CED + nt * 16 + n16]);
        }
    } else if (b < 1088) { // ---- init_s: 16 nodes, half h handles 8 nodes ----
        __shared__ float xs[16 * CFA];
        __shared__ float zs[16 * CLAT];
        __shared__ float tmp[16 * CIN];
        __shared__ float tv[16];
        int nb0 = (b - 960) * 16;
        int c = tid & 127, h = tid >> 7;
        if (tid < 16 * CFA / 4) ((float4*)xs)[tid] = ((const float4*)x)[nb0 * (CFA / 4) + tid];
        if (tid < 16 * CLAT / 4) ((float4*)zs)[tid] = ((const float4*)z)[nb0 * (CLAT / 4) + tid];
        if (tid < 16) tv[tid] = t[batch[nb0 + tid]];
        __syncthreads();
        float wta = Wt_a[c], base0 = b_atom[c] + bt_a[c];
        float acc[8];
#pragma unroll
        for (int q = 0; q < 8; q++) acc[q] = base0 + tv[h * 8 + q] * wta;
        for (int k = 0; k < CFA; k++) {
            float w = W_atom[k * CIN + c];
#pragma unroll
            for (int q = 0; q < 8; q++) acc[q] += xs[(h * 8 + q) * CFA + k] * w;
        }
#pragma unroll
        for (int q = 0; q < 8; q++) tmp[(h * 8 + q) * CIN + c] = acc[q];
        __syncthreads();
        float base1 = b_at[c] + b_lat[c];
        float acc2[8];
#pragma unroll
        for (int q = 0; q < 8; q++) acc2[q] = base1;
        for (int k4 = 0; k4 < CIN / 4; k4++) {
            float w0 = W_at[(4 * k4 + 0) * CIN + c], w1 = W_at[(4 * k4 + 1) * CIN + c];
            float w2 = W_at[(4 * k4 + 2) * CIN + c], w3 = W_at[(4 * k4 + 3) * CIN + c];
#pragma unroll
            for (int q = 0; q < 8; q++) {
                float4 f = *(const float4*)&tmp[(h * 8 + q) * CIN + 4 * k4];
                acc2[q] += f.x * w0 + f.y * w1 + f.z * w2 + f.w * w3;
            }
        }
        for (int k4 = 0; k4 < CLAT / 4; k4++) {
            float w0 = W_lat[(4 * k4 + 0) * CIN + c], w1 = W_lat[(4 * k4 + 1) * CIN + c];
            float w2 = W_lat[(4 * k4 + 2) * CIN + c], w3 = W_lat[(4 * k4 + 3) * CIN + c];
#pragma unroll
            for (int q = 0; q < 8; q++) {
                float4 f = *(const float4*)&zs[(h * 8 + q) * CLAT + 4 * k4];
                acc2[q] += f.x * w0 + f.y * w1 + f.z * w2 + f.w * w3;
            }
        }
#pragma unroll
        for (int q = 0; q < 8; q++) {
            int nd = nb0 + h * 8 + q;
            s[(size_t)nd * CIN + c] = acc2[q];
            s_bf[(size_t)nd * CIN + c] = f2bs(acc2[q]);
        }
    } else { // ---- cnt: degree count ----
        int base = (b - 1088) * 1024;
#pragma unroll
        for (int q = 0; q < 4; q++) {
            int k = base + q * 256 + tid;
            atomicAdd(&cnt[ii[k]], 1);
        }
    }
}

// ---------------- prefix sum over cnt[2048] -> rowpos (exclusive) ------------------------------
__global__ __launch_bounds__(256) void k_prefix(const int* __restrict__ cnt, int* __restrict__ rowpos)
{
    __shared__ int part[256];
    int tid = threadIdx.x;
    int loc[8], sum = 0;
#pragma unroll
    for (int q = 0; q < 8; q++) { loc[q] = cnt[tid * 8 + q]; sum += loc[q]; }
    part[tid] = sum;
    __syncthreads();
    if (tid == 0) {
        int r = 0;
        for (int i = 0; i < 256; i++) { int v = part[i]; part[i] = r; r += v; }
    }
    __syncthreads();
    int r = part[tid];
#pragma unroll
    for (int q = 0; q < 8; q++) { rowpos[tid * 8 + q] = r; r += loc[q]; }
}

// ---------------- build invp (orig k -> sorted pos) + i_s/j_s (sorted index arrays) ------------
__global__ void k_perm(const int* __restrict__ ii, const int* __restrict__ jj,
                       int* __restrict__ rowpos, int* __restrict__ invp,
                       int* __restrict__ i_s, int* __restrict__ j_s)
{
    int k = blockIdx.x * 256 + threadIdx.x;
    int iv = ii[k];
    int p = atomicAdd(&rowpos[iv], 1);
    invp[k] = p;
    i_s[p] = iv;
    j_s[p] = jj[k];
}

// ---------------- init e (writes SORTED order) + map scatter (original k) ----------------------
// 64 edges/block; W_bond/W_bt staged in LDS once per block.
__global__ __launch_bounds__(256) void k_init_e(
    const float* __restrict__ ea, const float* __restrict__ t,
    const int* __restrict__ beg, const int* __restrict__ jj, const int* __restrict__ ii,
    const int* __restrict__ invp,
    const float* __restrict__ Wt_b, const float* __restrict__ bt_b,
    const float* __restrict__ W_bond, const float* __restrict__ b_bond,
    const float* __restrict__ W_bt, const float* __restrict__ b_bt,
    float* __restrict__ e, short* __restrict__ e_bf, int* __restrict__ map)
{
    __shared__ float eas[64 * 5];
    __shared__ float tv[64];
    __shared__ int sp[64];
    __shared__ float tmp[64][33];
    __shared__ float wbt[32 * 32];
    __shared__ float wbond[5 * 32];
    __shared__ float cb[32], wtb[32], bbt2[32];
    int tid = threadIdx.x;
    int k0 = blockIdx.x * 64;
    for (int idx = tid; idx < 320; idx += 256) eas[idx] = ea[(size_t)k0 * 5 + idx];
    if (tid < 64) { tv[tid] = t[beg[k0 + tid]]; sp[tid] = invp[k0 + tid]; }
    for (int idx = tid; idx < 1024; idx += 256) wbt[idx] = W_bt[idx];
    if (tid < 160) wbond[tid] = W_bond[tid];
    if (tid < 32) { cb[tid] = b_bond[tid] + bt_b[tid]; wtb[tid] = Wt_b[tid]; bbt2[tid] = b_bt[tid]; }
    __syncthreads();
    int ch = tid & 31, eg = tid >> 5;
#pragma unroll
    for (int q = 0; q < 8; q++) {
        int le = eg * 8 + q;
        float acc = cb[ch] + tv[le] * wtb[ch];
#pragma unroll
        for (int bb = 0; bb < CNB; bb++) acc += eas[le * 5 + bb] * wbond[bb * 32 + ch];
        tmp[le][ch] = acc;
    }
    __syncthreads();
#pragma unroll
    for (int q = 0; q < 8; q++) {
        int le = eg * 8 + q;
        float acc2 = bbt2[ch];
        for (int d = 0; d < 32; d++) acc2 += tmp[le][d] * wbt[d * 32 + ch];
        size_t ix = (size_t)sp[le] * CED + ch;
        e[ix] = acc2;
        e_bf[ix] = f2bs(acc2);
        if (ch == 0) {
            int k = k0 + le;
            atomicMax(&map[(size_t)jj[k] * NN + ii[k]], k); // original-k max = numpy last-write-wins
        }
    }
}

// ---------------- node update + projections: 16 rows/block, waves split N ----------------------
template<bool DO_NODE>
__global__ __launch_bounds__(256) void k_node_proj(
    float* __restrict__ s, short* __restrict__ s_bf, float* __restrict__ agg,
    const short* __restrict__ Wpn_l, const float* __restrict__ bnode_l,
    const short* __restrict__ Wproj, float* __restrict__ U, float* __restrict__ V,
    float* __restrict__ P, float* __restrict__ Q)
{
    __shared__ short feat[16 * 264];
    __shared__ short feat2[16 * 136];
    int tid = threadIdx.x;
    int nb0 = blockIdx.x * 16;
    int lane = tid & 63, w = tid >> 6;
    int quad = lane >> 4, n16 = lane & 15;

    if (DO_NODE) {
        { // s_bf tile: 16 rows x 16 uint4
            int kl = tid >> 4, c = tid & 15;
            *(uint4*)&feat[kl * 264 + c * 8] = ((const uint4*)s_bf)[(size_t)(nb0 + kl) * 16 + c];
        }
        for (int idx = tid; idx < 16 * 32; idx += 256) { // agg -> bf16, zero agg
            int kl = idx >> 5, c = idx & 31;
            size_t gix = (size_t)(nb0 + kl) * 32 + c;
            float4 v = ((const float4*)agg)[gix];
            ((float4*)agg)[gix] = (float4){0.f, 0.f, 0.f, 0.f};
            uint2 p; p.x = pack2(v.x, v.y); p.y = pack2(v.z, v.w);
            *(uint2*)&feat[kl * 264 + 128 + 4 * c] = p;
        }
        __syncthreads();
        f32x4 acc[2];
        acc[0] = (f32x4){0.f, 0.f, 0.f, 0.f};
        acc[1] = (f32x4){0.f, 0.f, 0.f, 0.f};
        const short* fbase = feat + n16 * 264 + quad * 8;
#pragma unroll
        for (int kt = 0; kt < 8; kt++) {
            bf16x8 a = *(const bf16x8*)(fbase + kt * 32);
#pragma unroll
            for (int n2 = 0; n2 < 2; n2++) {
                int nt = w * 2 + n2;
                bf16x8 b = *(const bf16x8*)(Wpn_l + ((size_t)(kt * 8 + nt) * 64 + lane) * 8);
                acc[n2] = __builtin_amdgcn_mfma_f32_16x16x32_bf16(a, b, acc[n2], 0, 0, 0);
            }
        }
#pragma unroll
        for (int n2 = 0; n2 < 2; n2++) {
            int col = (w * 2 + n2) * 16 + n16;
            float bb = bnode_l[col];
#pragma unroll
            for (int r = 0; r < 4; r++) {
                int row = quad * 4 + r;
                size_t ix = (size_t)(nb0 + row) * CIN + col;
                float v = s[ix] + silu_f(acc[n2][r] + bb);
                s[ix] = v;
                short bv = f2bs(v);
                s_bf[ix] = bv;
                feat2[row * 136 + col] = bv;
            }
        }
        __syncthreads();
    } else {
        int kl = tid >> 4, c = tid & 15;
        *(uint4*)&feat2[kl * 136 + c * 8] = ((const uint4*)s_bf)[(size_t)(nb0 + kl) * 16 + c];
        __syncthreads();
    }

    // projections: [U|V|P|Q] = s_new @ Wproj (K=128, N=320); wave w -> nt 5w..5w+4
    f32x4 accp[5];
#pragma unroll
    for (int t2 = 0; t2 < 5; t2++) accp[t2] = (f32x4){0.f, 0.f, 0.f, 0.f};
    const short* abase = feat2 + n16 * 136 + quad * 8;
#pragma unroll
    for (int kt = 0; kt < 4; kt++) {
        bf16x8 a = *(const bf16x8*)(abase + kt * 32);
#pragma unroll
        for (int n5 = 0; n5 < 5; n5++) {
            int nt = w * 5 + n5;
            bf16x8 b = *(const bf16x8*)(Wproj + ((size_t)(kt * 20 + nt) * 64 + lane) * 8);
            accp[n5] = __builtin_amdgcn_mfma_f32_16x16x32_bf16(a, b, accp[n5], 0, 0, 0);
        }
    }
#pragma unroll
    for (int n5 = 0; n5 < 5; n5++) {
        int nt = w * 5 + n5;
#pragma unroll
        for (int r = 0; r < 4; r++) {
            int node = nb0 + quad * 4 + r;
            float v = accp[n5][r];
            if (nt < 8)       U[(size_t)node * CIN + nt * 16 + n16] = v;
            else if (nt < 16) V[(size_t)node * CIN + (nt - 8) * 16 + n16] = v;
            else if (nt < 18) P[(size_t)node * CED + (nt - 16) * 16 + n16] = v;
            else              Q[(size_t)node * CED + (nt - 18) * 16 + n16] = v;
        }
    }
}

// ---------------- per-edge (SORTED storage): [edge update] + [msg + segment sum] ---------------
// Block p owns contiguous sorted rows 64p..64p+63: e/e_bf fully coalesced; i_s/j_s coalesced.
template<bool DO_EDGE, bool DO_MSG>
__global__ __launch_bounds__(256) void k_em(
    const short* __restrict__ e_bf_in,
    const int* __restrict__ i_s, const int* __restrict__ j_s,
    const short* __restrict__ We3p, const float* __restrict__ bedge,
    const float* __restrict__ P, const float* __restrict__ Q,
    float* __restrict__ e, short* __restrict__ e_bf,
    const short* __restrict__ W3mp, const float* __restrict__ bmsg,
    const float* __restrict__ U, const float* __restrict__ V,
    float* __restrict__ agg)
{
    __shared__ short feat_e[64 * 40]; // e rows bf16 (32 used, pad 40)
    __shared__ float uv[64 * 132];    // U[i]+V[j]; after msg epilogue holds m values
    __shared__ float pq[64 * 36];     // P[i]+Q[j]
    __shared__ int sii[64], sjj[64];
    int tid = threadIdx.x;
    int e0 = blockIdx.x * 64;
    if (tid < 64) sii[tid] = i_s[e0 + tid];       // sorted non-decreasing
    else if (tid < 128) sjj[tid - 64] = j_s[e0 + tid - 64];
    __syncthreads();
    { // stage e rows: contiguous 4KB
        int kl = tid >> 2, c = tid & 3;
        uint4 v = ((const uint4*)e_bf_in)[(size_t)e0 * 4 + tid];
        *(uint4*)&feat_e[kl * 40 + c * 8] = v;
    }
    if (DO_EDGE) {
        for (int idx = tid; idx < 64 * 8; idx += 256) { // pq rows
            int kl = idx >> 3, c = idx & 7;
            float4 a = ((const float4*)P)[(size_t)sii[kl] * 8 + c];
            float4 b = ((const float4*)Q)[(size_t)sjj[kl] * 8 + c];
            *(float4*)&pq[kl * 36 + 4 * c] = (float4){a.x + b.x, a.y + b.y, a.z + b.z, a.w + b.w};
        }
    }
    if (DO_MSG) {
        for (int idx = tid; idx < 64 * 32; idx += 256) { // uv rows
            int kl = idx >> 5, c = idx & 31;
            float4 a = ((const float4*)U)[(size_t)sii[kl] * 32 + c];
            float4 b = ((const float4*)V)[(size_t)sjj[kl] * 32 + c];
            *(float4*)&uv[kl * 132 + 4 * c] = (float4){a.x + b.x, a.y + b.y, a.z + b.z, a.w + b.w};
        }
    }
    __syncthreads();
    int lane = tid & 63, w = tid >> 6;
    int quad = lane >> 4, n16 = lane & 15;
    const short* abase = feat_e + (w * 16 + n16) * 40 + quad * 8;
    bf16x8 a = *(const bf16x8*)abase;

    if (DO_EDGE) {
        f32x4 acc_e[2];
        acc_e[0] = (f32x4){0.f, 0.f, 0.f, 0.f};
        acc_e[1] = (f32x4){0.f, 0.f, 0.f, 0.f};
#pragma unroll
        for (int nt = 0; nt < 2; nt++) {
            bf16x8 b = *(const bf16x8*)(We3p + ((size_t)(nt * 64 + lane)) * 8);
            acc_e[nt] = __builtin_amdgcn_mfma_f32_16x16x32_bf16(a, b, acc_e[nt], 0, 0, 0);
        }
#pragma unroll
        for (int nt = 0; nt < 2; nt++) {
            int ch = nt * 16 + n16;
            float bb = bedge[ch];
#pragma unroll
            for (int r = 0; r < 4; r++) {
                int el = w * 16 + quad * 4 + r;            // own-wave row
                size_t ix = (size_t)(e0 + el) * CED + ch;  // contiguous
                float v = e[ix] + silu_f(acc_e[nt][r] + bb + pq[el * 36 + ch]);
                e[ix] = v;
                short bv = f2bs(v);
                e_bf[ix] = bv;
                feat_e[el * 40 + ch] = bv; // patch for msg A
            }
        }
        a = *(const bf16x8*)abase; // re-read patched row (own-wave rows; lgkmcnt ordered)
    }

    if (DO_MSG) {
        f32x4 acc_m[8];
#pragma unroll
        for (int t2 = 0; t2 < 8; t2++) acc_m[t2] = (f32x4){0.f, 0.f, 0.f, 0.f};
#pragma unroll
        for (int nt = 0; nt < 8; nt++) {
            bf16x8 b = *(const bf16x8*)(W3mp + ((size_t)(nt * 64 + lane)) * 8);
            acc_m[nt] = __builtin_amdgcn_mfma_f32_16x16x32_bf16(a, b, acc_m[nt], 0, 0, 0);
        }
#pragma unroll
        for (int nt = 0; nt < 8; nt++) {
            int ch = nt * 16 + n16;
            float bb = bmsg[ch];
#pragma unroll
            for (int r = 0; r < 4; r++) {
                int el = w * 16 + quad * 4 + r;
                int lix = el * 132 + ch;
                float m = silu_f(acc_m[nt][r] + bb + uv[lix]); // (el,ch) owned by this thread
                uv[lix] = m;
            }
        }
        __syncthreads();
        if (tid < 128) { // group-reduce by sorted target
            int c = tid;
            float run = 0.f;
            int cur = sii[0];
            for (int r = 0; r < 64; r++) {
                int tg = sii[r];
                if (tg != cur) { atomicAdd(&agg[(size_t)cur * CIN + c], run); run = 0.f; cur = tg; }
                run += uv[r * 132 + c];
            }
            atomicAdd(&agg[(size_t)cur * CIN + c], run);
        }
    }
}

// ---------------- post node: 16 rows/block, waves split N --------------------------------------
__global__ __launch_bounds__(256) void k_post_node_mfma(
    const short* __restrict__ s_bf,
    const short* __restrict__ Wpsh, const float* __restrict__ bsh,
    const short* __restrict__ Wpal, const float* __restrict__ bal,
    float* __restrict__ s2, float* __restrict__ out)
{
    __shared__ short feat[16 * 136];
    __shared__ short feat_s2[16 * 136];
    int tid = threadIdx.x;
    int nb0 = blockIdx.x * 16;
    int lane = tid & 63, w = tid >> 6;
    int quad = lane >> 4, n16 = lane & 15;
    {
        int kl = tid >> 4, c = tid & 15;
        *(uint4*)&feat[kl * 136 + c * 8] = ((const uint4*)s_bf)[(size_t)(nb0 + kl) * 16 + c];
    }
    __syncthreads();
    const short* fbase = feat + n16 * 136 + quad * 8;
    f32x4 acc[2];
    acc[0] = (f32x4){0.f, 0.f, 0.f, 0.f};
    acc[1] = (f32x4){0.f, 0.f, 0.f, 0.f};
#pragma unroll
    for (int kt = 0; kt < 4; kt++) {
        bf16x8 a = *(const bf16x8*)(fbase + kt * 32);
#pragma unroll
        for (int n2 = 0; n2 < 2; n2++) {
            int nt = w * 2 + n2;
            bf16x8 b = *(const bf16x8*)(Wpsh + ((size_t)(kt * 8 + nt) * 64 + lane) * 8);
            acc[n2] = __builtin_amdgcn_mfma_f32_16x16x32_bf16(a, b, acc[n2], 0, 0, 0);
        }
    }
#pragma unroll
    for (int n2 = 0; n2 < 2; n2++) {
        int col = (w * 2 + n2) * 16 + n16;
        float bb = bsh[col];
#pragma unroll
        for (int r = 0; r < 4; r++) {
            int row = quad * 4 + r;
            float v = silu_f(acc[n2][r] + bb);
            s2[(size_t)(nb0 + row) * CIN + col] = v;
            feat_s2[row * 136 + col] = f2bs(v);
        }
    }
    __syncthreads();
    const short* abase = feat_s2 + n16 * 136 + quad * 8;
    f32x4 acca[2];
    acca[0] = (f32x4){0.f, 0.f, 0.f, 0.f};
    acca[1] = (f32x4){0.f, 0.f, 0.f, 0.f};
    int nAl = (w == 0) ? 2 : 1;
    int ntl[2] = {w, 4};
#pragma unroll
    for (int kt = 0; kt < 4; kt++) {
        bf16x8 a = *(const bf16x8*)(abase + kt * 32);
#pragma unroll
        for (int q = 0; q < 2; q++) {
            if (q < nAl) {
                bf16x8 b = *(const bf16x8*)(Wpal + ((size_t)(kt * 5 + ntl[q]) * 64 + lane) * 8);
                acca[q] = __builtin_amdgcn_mfma_f32_16x16x32_bf16(a, b, acca[q], 0, 0, 0);
            }
        }
    }
#pragma unroll
    for (int q = 0; q < 2; q++) {
        if (q < nAl) {
            int col = ntl[q] * 16 + n16;
            float bb = bal[col];
#pragma unroll
            for (int r = 0; r < 4; r++) {
                int node = nb0 + quad * 4 + r;
                float v = acca[q][r] + bb;
                if (col < CFA) out[OFF_AT + node * CFA + col] = v;
                else           out[(size_t)node * CLAT + (col - CFA)] = v;
            }
        }
    }
}

// ---------------- post edge (MFMA): esym@Wbm + silu + Wbl tail (e in SORTED order) -------------
__global__ __launch_bounds__(256) void k_post_edge_mfma(
    const float* __restrict__ s2, const float* __restrict__ e,
    const int* __restrict__ ii, const int* __restrict__ jj,
    const int* __restrict__ map, const int* __restrict__ invp,
    const short* __restrict__ Wpbm, const float* __restrict__ bbm,
    const float* __restrict__ Wbl, const float* __restrict__ bbl,
    float* __restrict__ out)
{
    __shared__ int sii[64], sjj[64], skf[64], skb[64];
    __shared__ short esym[64 * 40];
    __shared__ float sbias[64 * 132]; // later aliased as fshT[128][66]
    int tid = threadIdx.x;
    int e0 = blockIdx.x * 64;
    if (tid < 64) sii[tid] = ii[e0 + tid];
    else if (tid < 128) sjj[tid - 64] = jj[e0 + tid - 64];
    __syncthreads();
    if (tid < 64) skf[tid] = invp[map[(size_t)sjj[tid] * NN + sii[tid]]]; // always set by edge itself
    else if (tid < 128) {
        int m = map[(size_t)sii[tid - 64] * NN + sjj[tid - 64]];
        skb[tid - 64] = (m >= 0) ? invp[m] : -1;
    }
    __syncthreads();
    for (int idx = tid; idx < 64 * 8; idx += 256) {
        int kl = idx >> 3, c = idx & 7;
        float4 a = ((const float4*)e)[(size_t)skf[kl] * 8 + c];
        int kb = skb[kl];
        float4 b = {0.f, 0.f, 0.f, 0.f};
        if (kb >= 0) b = ((const float4*)e)[(size_t)kb * 8 + c];
        uint2 p; p.x = pack2(0.5f * (a.x + b.x), 0.5f * (a.y + b.y));
        p.y = pack2(0.5f * (a.z + b.z), 0.5f * (a.w + b.w));
        *(uint2*)&esym[kl * 40 + 4 * c] = p;
    }
    for (int idx = tid; idx < 64 * 32; idx += 256) {
        int kl = idx >> 5, c = idx & 31;
        float4 a = ((const float4*)s2)[(size_t)sii[kl] * 32 + c];
        float4 b = ((const float4*)s2)[(size_t)sjj[kl] * 32 + c];
        float4 v = {a.x + b.x, a.y + b.y, a.z + b.z, a.w + b.w};
        *(float4*)&sbias[kl * 132 + 4 * c] = v;
    }
    __syncthreads();
    int lane = tid & 63, w = tid >> 6;
    int quad = lane >> 4, n16 = lane & 15;
    bf16x8 a = *(const bf16x8*)(esym + (w * 16 + n16) * 40 + quad * 8);
    f32x4 acc[8];
#pragma unroll
    for (int nt = 0; nt < 8; nt++) {
        bf16x8 b = *(const bf16x8*)(Wpbm + ((size_t)nt * 64 + lane) * 8);
        f32x4 zero = {0.f, 0.f, 0.f, 0.f};
        acc[nt] = __builtin_amdgcn_mfma_f32_16x16x32_bf16(a, b, zero, 0, 0, 0);
    }
    float f[8][4];
#pragma unroll
    for (int nt = 0; nt < 8; nt++) {
        int col = nt * 16 + n16;
        float bb = bbm[col];
#pragma unroll
        for (int r = 0; r < 4; r++) {
            int row = w * 16 + quad * 4 + r;
            f[nt][r] = silu_f(acc[nt][r] + bb + sbias[row * 132 + col]);
        }
    }
    __syncthreads();
    float* fshT = sbias;
#pragma unroll
    for (int nt = 0; nt < 8; nt++) {
        int col = nt * 16 + n16;
#pragma unroll
        for (int r = 0; r < 4; r++) {
            int row = w * 16 + quad * 4 + r;
            fshT[col * 66 + row] = f[nt][r];
        }
    }
    __syncthreads();
    for (int idx = tid; idx < 64 * CNB; idx += 256) {
        int kl = idx / CNB, b = idx - kl * CNB;
        float acc3 = bbl[b];
        for (int d = 0; d < CIN; d++) acc3 += fshT[d * 66 + kl] * Wbl[d * CNB + b];
        out[OFF_B + (size_t)(e0 + kl) * CNB + b] = acc3;
    }
}

extern "C" void kernel_launch(void* const* d_in, const int* in_sizes, int n_in,
                              void* d_out, int out_size, void* d_ws, size_t ws_size,
                              hipStream_t stream) {
    const float* x      = (const float*)d_in[0];
    const float* t      = (const float*)d_in[1];
    const float* z      = (const float*)d_in[2];
    const int*   eidx   = (const int*)d_in[3];
    const int*   jj     = eidx;        // edge_index[0] = j
    const int*   ii     = eidx + NE;   // edge_index[1] = i
    const float* ea     = (const float*)d_in[4];
    const int*   batch  = (const int*)d_in[5];
    const int*   beg    = (const int*)d_in[6];
    const float* Wt_a   = (const float*)d_in[7];
    const float* bt_a   = (const float*)d_in[8];
    const float* Wt_b   = (const float*)d_in[9];
    const float* bt_b   = (const float*)d_in[10];
    const float* W_atom = (const float*)d_in[11];
    const float* b_atom = (const float*)d_in[12];
    const float* W_bond = (const float*)d_in[13];
    const float* b_bond = (const float*)d_in[14];
    const float* W_lat  = (const float*)d_in[15];
    const float* b_lat  = (const float*)d_in[16];
    const float* W_at   = (const float*)d_in[17];
    const float* b_at   = (const float*)d_in[18];
    const float* W_bt   = (const float*)d_in[19];
    const float* b_bt   = (const float*)d_in[20];
    const float* Wmsg   = (const float*)d_in[21];
    const float* bmsg   = (const float*)d_in[22];
    const float* Wnode  = (const float*)d_in[23];
    const float* bnode  = (const float*)d_in[24];
    const float* Wedge  = (const float*)d_in[25];
    const float* bedge  = (const float*)d_in[26];
    const float* Wsh    = (const float*)d_in[27];
    const float* bsh    = (const float*)d_in[28];
    const float* Wbm    = (const float*)d_in[29];
    const float* bbm    = (const float*)d_in[30];
    const float* Wbl    = (const float*)d_in[31];
    const float* bbl    = (const float*)d_in[32];
    const float* Wal    = (const float*)d_in[33];
    const float* bal    = (const float*)d_in[34];

    float* s      = (float*)d_ws;                       // N*128 f32
    float* e      = s + (size_t)NN * CIN;               // E*32 f32 (SORTED order)
    float* agg    = e + (size_t)NE * CED;               // N*128 f32
    int*   cnt    = (int*)(agg + (size_t)NN * CIN);     // N (zeroed with agg)
    int*   rowpos = cnt + NN;                           // N
    int*   invp   = rowpos + NN;                        // E
    int*   i_s    = invp + NE;                          // E
    int*   j_s    = i_s + NE;                           // E
    float* s2     = (float*)(j_s + NE);                 // N*128
    float* U      = s2 + (size_t)NN * CIN;              // N*128
    float* V      = U + (size_t)NN * CIN;               // N*128
    float* P      = V + (size_t)NN * CIN;               // N*32
    float* Q      = P + (size_t)NN * CED;               // N*32
    int*   map    = (int*)(Q + (size_t)NN * CED);       // N*N
    short* s_bf   = (short*)(map + (size_t)NN * NN);    // N*128 bf16
    short* e_bf   = s_bf + (size_t)NN * CIN;            // E*32 bf16 (SORTED order)
    short* Wpn    = e_bf + (size_t)NE * CED;            // 163840
    short* Wpsh   = Wpn + (size_t)NL * 8 * 8 * 64 * 8;  // 16384
    short* Wpal   = Wpsh + (size_t)4 * 8 * 64 * 8;      // 10240
    short* Wpbm   = Wpal + (size_t)4 * 5 * 64 * 8;      // 4096
    short* Wproj  = Wpbm + (size_t)8 * 64 * 8;          // 245760 (6 slots x 40960)
    short* W3m    = Wproj + (size_t)6 * 4 * 20 * 64 * 8;// 20480
    short* We3    = W3m + (size_t)NL * 8 * 64 * 8;      // 5120
    float* out    = (float*)d_out;

    hipMemsetAsync(map, 0xFF, (size_t)NN * NN * sizeof(int), stream);
    hipMemsetAsync(agg, 0, ((size_t)NN * CIN + NN) * sizeof(float), stream); // agg + cnt
    k_prologue<<<1152, 256, 0, stream>>>(Wmsg, Wedge, Wnode, Wsh, Wal, Wbm,
                                         Wpn, Wpsh, Wpal, Wpbm, Wproj, W3m, We3,
                                         x, t, z, batch, Wt_a, bt_a, W_atom, b_atom,
                                         W_lat, b_lat, W_at, b_at, s, s_bf, ii, cnt);
    k_prefix<<<1, 256, 0, stream>>>(cnt, rowpos);
    k_perm<<<NE / 256, 256, 0, stream>>>(ii, jj, rowpos, invp, i_s, j_s);
    k_init_e<<<NE / 64, 256, 0, stream>>>(ea, t, beg, jj, ii, invp, Wt_b, bt_b,
                                          W_bond, b_bond, W_bt, b_bt, e, e_bf, map);

    // proj0: U,V from s_0 with Wmsg_0 (slot 0)
    k_node_proj<false><<<NN / 16, 256, 0, stream>>>(s, s_bf, agg, nullptr, nullptr,
                                                    Wproj, U, V, P, Q);
    // msg0
    k_em<false, true><<<NE / 64, 256, 0, stream>>>(e_bf, i_s, j_s,
                                                   nullptr, nullptr, P, Q, e, e_bf,
                                                   W3m, bmsg, U, V, agg);
    for (int l = 0; l < NL; l++) {
        // node_l + projections (slot l+1: msg_{l+1}, edge_l)
        k_node_proj<true><<<NN / 16, 256, 0, stream>>>(s, s_bf, agg,
                                                       Wpn + (size_t)l * 8 * 8 * 64 * 8,
                                                       bnode + l * CIN,
                                                       Wproj + (size_t)(l + 1) * 4 * 20 * 64 * 8,
                                                       U, V, P, Q);
        if (l < NL - 1) {
            k_em<true, true><<<NE / 64, 256, 0, stream>>>(e_bf, i_s, j_s,
                                                          We3 + (size_t)l * 2 * 64 * 8,
                                                          bedge + l * CED, P, Q, e, e_bf,
                                                          W3m + (size_t)(l + 1) * 8 * 64 * 8,
                                                          bmsg + (l + 1) * CIN, U, V, agg);
        } else {
            k_em<true, false><<<NE / 64, 256, 0, stream>>>(e_bf, i_s, j_s,
                                                           We3 + (size_t)l * 2 * 64 * 8,
                                                           bedge + l * CED, P, Q, e, e_bf,
                                                           nullptr, nullptr, nullptr, nullptr, agg);
        }
    }
    k_post_node_mfma<<<NN / 16, 256, 0, stream>>>(s_bf, Wpsh, bsh, Wpal, bal, s2, out);
    k_post_edge_mfma<<<NE / 64, 256, 0, stream>>>(s2, e, ii, jj, map, invp,
                                                  Wpbm, bbm, Wbl, bbl, out);
}